// Round 16
// baseline (46.774 us; speedup 1.0000x reference)
//
#include <hip/hip_runtime.h>

#define B_N 262144
#define OBS_N 8

typedef __attribute__((ext_vector_type(4))) _Float16 f16x4;
typedef __attribute__((ext_vector_type(2))) __fp16 fp16x2;
typedef __attribute__((ext_vector_type(4))) float f32x4;

#define LOG2E 1.44269504088896340736f

__device__ __forceinline__ float rcpf_(float x){ return __builtin_amdgcn_rcpf(x); }
__device__ __forceinline__ float exp2f_(float x){ return __builtin_amdgcn_exp2f(x); }
// exact for all signs: tanh(x) = 1 - 2/(exp2(2*log2e*x)+1)
__device__ __forceinline__ float tanh_(float x){ return fmaf(-2.0f, rcpf_(exp2f_((2.0f*LOG2E) * x) + 1.0f), 1.0f); }

__device__ __forceinline__ f16x4 pack4(float a, float b, float c, float d){
    fp16x2 lo = __builtin_amdgcn_cvt_pkrtz(a, b);
    fp16x2 hi = __builtin_amdgcn_cvt_pkrtz(c, d);
    f16x4 r;
    r[0] = (_Float16)lo[0]; r[1] = (_Float16)lo[1];
    r[2] = (_Float16)hi[0]; r[3] = (_Float16)hi[1];
    return r;
}

#define MFMA16(a, b, c) __builtin_amdgcn_mfma_f32_16x16x16f16((a), (b), (c), 0, 0, 0)

// Layout (v_mfma_f32_16x16x16_f16):
//   A: lane holds A[row = lane&15][k = 4*(lane>>4)+i]
//   B: lane holds B[k = 4*(lane>>4)+i][col = lane&15]
//   C/D: lane holds C[row = 4*(lane>>4)+r][col = lane&15]
// => D layout == next-GEMM B layout (batch in columns): recurrence needs no shuffle.
//
// R16 = R9 + ANTI-PHASE TILE PIPELINE (register-neutral reorder):
//   issue gB -> cellA (hides gB latency) -> issue gA(t+1) -> cellB (hides gA).
//   Peak acc regs unchanged (gA+gB = 32, same as R9). traj has OBS_N+1 rows,
//   so the trailing dead gA issue at t=7 reads a valid row.
__global__ __launch_bounds__(256, 4) void goal_kernel(
    const float* __restrict__ traj,
    const float* __restrict__ obsp,
    const float* __restrict__ h0,
    const float* __restrict__ c0,
    const float* __restrict__ noise,
    const float* __restrict__ encW,
    const float* __restrict__ encb,
    const float* __restrict__ Wih,
    const float* __restrict__ Whh,
    const float* __restrict__ bih,
    const float* __restrict__ bhh,
    const float* __restrict__ jW,
    const float* __restrict__ jb,
    const float* __restrict__ cW,
    const float* __restrict__ hW,
    const float* __restrict__ hb,
    const float* __restrict__ oW,
    const float* __restrict__ ob,
    float* __restrict__ out)
{
    const int lane = threadIdx.x & 63;
    const int wv   = threadIdx.x >> 6;
    const int q    = lane >> 4;
    const int s    = lane & 15;
    const int j4   = q * 4;
    const int base = blockIdx.x * 128 + wv * 32;   // 32 batch cols per wave
    const int colA = base + s;
    const int colB = base + 16 + s;

    // ---- preload (once), f16-compressed ----
    f16x4 ew0h, ew1h, ebh;
    #pragma unroll
    for (int r = 0; r < 4; ++r) {
        ew0h[r] = (_Float16)encW[(j4 + r) * 2 + 0];
        ew1h[r] = (_Float16)encW[(j4 + r) * 2 + 1];
        ebh[r]  = (_Float16)encb[j4 + r];
    }

    // gate exp2-arg pre-scaling folded into weights+bias:
    // i,f,o: * -log2e ; g: * -2log2e
    const float gsc[4] = { -LOG2E, -LOG2E, -2.0f*LOG2E, -LOG2E };

    f16x4 wihA[4], whhA[4], biasH[4];
    #pragma unroll
    for (int m = 0; m < 4; ++m) {
        float4 wa = *(const float4*)(Wih + (16 * m + s) * 16 + j4);
        float4 wb = *(const float4*)(Whh + (16 * m + s) * 16 + j4);
        wihA[m] = pack4(wa.x*gsc[m], wa.y*gsc[m], wa.z*gsc[m], wa.w*gsc[m]);
        whhA[m] = pack4(wb.x*gsc[m], wb.y*gsc[m], wb.z*gsc[m], wb.w*gsc[m]);
        float4 b1 = *(const float4*)(bih + 16 * m + j4);
        float4 b2 = *(const float4*)(bhh + 16 * m + j4);
        biasH[m] = pack4((b1.x+b2.x)*gsc[m], (b1.y+b2.y)*gsc[m],
                         (b1.z+b2.z)*gsc[m], (b1.w+b2.w)*gsc[m]);
    }

    // state (two independent column tiles)
    f32x4 cA = *(const f32x4*)(c0 + colA * 16 + j4);
    f32x4 cB = *(const f32x4*)(c0 + colB * 16 + j4);
    float4 hA0 = *(const float4*)(h0 + colA * 16 + j4);
    float4 hB0 = *(const float4*)(h0 + colB * 16 + j4);
    f16x4 hA = pack4(hA0.x, hA0.y, hA0.z, hA0.w);
    f16x4 hB = pack4(hB0.x, hB0.y, hB0.z, hB0.w);

    float2 nzA = *(const float2*)(noise + colA * 2);
    float2 nzB = *(const float2*)(noise + colB * 2);

    const float NEG2L2E = -2.0f * LOG2E;

    // ---------------- LSTM encoder (anti-phase tile pipeline) ----------------
    float2 xB = *(const float2*)(traj + colB * 2);

    f32x4 gA[4], gB[4];
    // prologue: issue tile-A step-0 gates
    {
        float2 xA0 = *(const float2*)(traj + colA * 2);
        _Float16 ax = (_Float16)xA0.x, ay = (_Float16)xA0.y;
        f16x4 xx = { ax, ax, ax, ax }, yy = { ay, ay, ay, ay };
        f16x4 eA = ew0h * xx + ew1h * yy + ebh;
        #pragma unroll
        for (int r = 0; r < 4; ++r) eA[r] = eA[r] > (_Float16)0 ? eA[r] : (_Float16)0;
        #pragma unroll
        for (int m = 0; m < 4; ++m) {
            f32x4 bv;
            bv[0] = (float)biasH[m][0]; bv[1] = (float)biasH[m][1];
            bv[2] = (float)biasH[m][2]; bv[3] = (float)biasH[m][3];
            gA[m] = MFMA16(wihA[m], eA, bv);
            gA[m] = MFMA16(whhA[m], hA, gA[m]);
        }
    }

    #pragma unroll 1
    for (int t = 0; t < OBS_N; ++t) {
        // ---- issue tile-B gates for step t (needs hB(t), xB(t)) ----
        {
            _Float16 bx = (_Float16)xB.x, by = (_Float16)xB.y;
            f16x4 xx = { bx, bx, bx, bx }, yy = { by, by, by, by };
            f16x4 eB = ew0h * xx + ew1h * yy + ebh;
            #pragma unroll
            for (int r = 0; r < 4; ++r) eB[r] = eB[r] > (_Float16)0 ? eB[r] : (_Float16)0;
            #pragma unroll
            for (int m = 0; m < 4; ++m) {
                f32x4 bv;
                bv[0] = (float)biasH[m][0]; bv[1] = (float)biasH[m][1];
                bv[2] = (float)biasH[m][2]; bv[3] = (float)biasH[m][3];
                gB[m] = MFMA16(wihA[m], eB, bv);
                gB[m] = MFMA16(whhA[m], hB, gB[m]);
            }
        }

        // prefetch x(t+1) — row t+1 <= OBS_N is always valid (traj has OBS_N+1 rows)
        float2 nxA = *(const float2*)(traj + (t + 1) * (B_N * 2) + colA * 2);
        float2 nxB = *(const float2*)(traj + (t + 1) * (B_N * 2) + colB * 2);

        // ---- cell A: consume gA -> hA(t+1). Trans burst hides gB latency ----
        {
            float hn[4];
            #pragma unroll
            for (int r = 0; r < 4; ++r) {
                float Ei = exp2f_(gA[0][r]);
                float Ef = exp2f_(gA[1][r]);
                float Eg = exp2f_(gA[2][r]);
                float Eo = exp2f_(gA[3][r]);
                float pi = 1.0f + Ei, pg = 1.0f + Eg, pf = 1.0f + Ef;
                float m_ = pi * pg;
                float R1 = rcpf_(m_ * pf);
                float cn = fmaf(cA[r], m_, fmaf(-Eg, pf, pf)) * R1;
                cA[r] = cn;
                float Ec = exp2f_(NEG2L2E * cn);
                float R2 = rcpf_((1.0f + Ec) * (1.0f + Eo));
                hn[r] = fmaf(-Ec, R2, R2);
            }
            hA = pack4(hn[0], hn[1], hn[2], hn[3]);
        }

        // ---- issue tile-A gates for step t+1 (needs new hA, x(t+1)) ----
        // (at t = OBS_N-1 this issues dead gates from valid row OBS_N; harmless)
        {
            _Float16 ax = (_Float16)nxA.x, ay = (_Float16)nxA.y;
            f16x4 xx = { ax, ax, ax, ax }, yy = { ay, ay, ay, ay };
            f16x4 eA = ew0h * xx + ew1h * yy + ebh;
            #pragma unroll
            for (int r = 0; r < 4; ++r) eA[r] = eA[r] > (_Float16)0 ? eA[r] : (_Float16)0;
            #pragma unroll
            for (int m = 0; m < 4; ++m) {
                f32x4 bv;
                bv[0] = (float)biasH[m][0]; bv[1] = (float)biasH[m][1];
                bv[2] = (float)biasH[m][2]; bv[3] = (float)biasH[m][3];
                gA[m] = MFMA16(wihA[m], eA, bv);
                gA[m] = MFMA16(whhA[m], hA, gA[m]);
            }
        }

        // ---- cell B: consume gB -> hB(t+1). Trans burst hides gA latency ----
        {
            float hn[4];
            #pragma unroll
            for (int r = 0; r < 4; ++r) {
                float Ei = exp2f_(gB[0][r]);
                float Ef = exp2f_(gB[1][r]);
                float Eg = exp2f_(gB[2][r]);
                float Eo = exp2f_(gB[3][r]);
                float pi = 1.0f + Ei, pg = 1.0f + Eg, pf = 1.0f + Ef;
                float m_ = pi * pg;
                float R1 = rcpf_(m_ * pf);
                float cn = fmaf(cB[r], m_, fmaf(-Eg, pf, pf)) * R1;
                cB[r] = cn;
                float Ec = exp2f_(NEG2L2E * cn);
                float R2 = rcpf_((1.0f + Ec) * (1.0f + Eo));
                hn[r] = fmaf(-Ec, R2, R2);
            }
            hB = pack4(hn[0], hn[1], hn[2], hn[3]);
        }

        xB = nxB;
    }

    // ---------------- MAF sample ----------------
    float x0A = nzA.x, x1A = nzA.y;
    float x0B = nzB.x, x1B = nzB.y;

    #pragma unroll 1
    for (int kf = 3; kf >= 0; --kf) {
        float tA = x0A; x0A = x1A; x1A = tA;
        float tB = x0B; x0B = x1B; x1B = tB;

        float ob0 = ob[kf*4 + 0], ob1 = ob[kf*4 + 1];
        float ob2 = ob[kf*4 + 2], ob3 = ob[kf*4 + 3] * 0.2f;
        // i=0: rows 0,2 fully masked -> flow constants
        float ea0 = exp2f_(7.2134752044f * tanh_(ob2 * 0.2f));  // e^{5 tanh(ob2/5)}
        x0A = fmaf(x0A, ea0, ob0);
        x0B = fmaf(x0B, ea0, ob0);

        // per-flow weights (shared by both column tiles)
        float4 cw = *(const float4*)(cW + kf * 256 + s * 16 + j4);
        f16x4 cwA = pack4(cw.x, cw.y, cw.z, cw.w);
        float4 hw = *(const float4*)(hW + kf * 256 + s * 16 + j4);
        f16x4 hwA = pack4(hw.x, hw.y, hw.z, hw.w);
        // oW rows replicated period-4; row 3 pre-scaled by 1/CLAMP
        float osc = ((s & 3) == 3) ? 0.2f : 1.0f;
        float4 ow = *(const float4*)(oW + kf * 64 + (s & 3) * 16 + j4);
        f16x4 owA = pack4(ow.x * osc, ow.y * osc, ow.z * osc, ow.w * osc);

        // i=1: h1 = relu(jW0*x0 + jb + cW@h)
        f32x4 a1A, a1B;
        #pragma unroll
        for (int r = 0; r < 4; ++r) {
            float jwv = jW[kf * 32 + (j4 + r) * 2];
            float jbv = jb[kf * 16 + j4 + r];
            a1A[r] = fmaf(jwv, x0A, jbv);
            a1B[r] = fmaf(jwv, x0B, jbv);
        }
        a1A = MFMA16(cwA, hA, a1A);
        a1B = MFMA16(cwA, hB, a1B);
        f16x4 h1A = pack4(fmaxf(a1A[0],0.f), fmaxf(a1A[1],0.f), fmaxf(a1A[2],0.f), fmaxf(a1A[3],0.f));
        f16x4 h1B = pack4(fmaxf(a1B[0],0.f), fmaxf(a1B[1],0.f), fmaxf(a1B[2],0.f), fmaxf(a1B[3],0.f));

        f32x4 a2A, a2B;
        #pragma unroll
        for (int r = 0; r < 4; ++r) { float hbv = hb[kf * 16 + j4 + r]; a2A[r] = hbv; a2B[r] = hbv; }
        a2A = MFMA16(hwA, h1A, a2A);
        a2B = MFMA16(hwA, h1B, a2B);
        f16x4 h2A = pack4(fmaxf(a2A[0],0.f), fmaxf(a2A[1],0.f), fmaxf(a2A[2],0.f), fmaxf(a2A[3],0.f));
        f16x4 h2B = pack4(fmaxf(a2B[0],0.f), fmaxf(a2B[1],0.f), fmaxf(a2B[2],0.f), fmaxf(a2B[3],0.f));

        f32x4 a3A, a3B;
        a3A[0] = ob0; a3A[1] = ob1; a3A[2] = ob2; a3A[3] = ob3;
        a3B = a3A;
        a3A = MFMA16(owA, h2A, a3A);
        a3B = MFMA16(owA, h2B, a3B);

        // row 3 already × 0.2 ; x1 = x1*e^{5 tanh(.)} + m1
        x1A = fmaf(x1A, exp2f_(7.2134752044f * tanh_(a3A[3])), a3A[1]);
        x1B = fmaf(x1B, exp2f_(7.2134752044f * tanh_(a3B[3])), a3B[1]);
    }

    if (q == 0) {
        float2 ppA = *(const float2*)(obsp + (OBS_N - 1) * (B_N * 2) + colA * 2);
        float2 ppB = *(const float2*)(obsp + (OBS_N - 1) * (B_N * 2) + colB * 2);
        float2 oA; oA.x = x0A + ppA.x; oA.y = x1A + ppA.y;
        float2 oB; oB.x = x0B + ppB.x; oB.y = x1B + ppB.y;
        *(float2*)(out + colA * 2) = oA;
        *(float2*)(out + colB * 2) = oB;
    }
}

extern "C" void kernel_launch(void* const* d_in, const int* in_sizes, int n_in,
                              void* d_out, int out_size, void* d_ws, size_t ws_size,
                              hipStream_t stream) {
    goal_kernel<<<B_N / 128, 256, 0, stream>>>(
        (const float*)d_in[0],  (const float*)d_in[1],  (const float*)d_in[2],
        (const float*)d_in[3],  (const float*)d_in[4],  (const float*)d_in[5],
        (const float*)d_in[6],  (const float*)d_in[7],  (const float*)d_in[8],
        (const float*)d_in[9],  (const float*)d_in[10], (const float*)d_in[11],
        (const float*)d_in[12], (const float*)d_in[13], (const float*)d_in[14],
        (const float*)d_in[15], (const float*)d_in[16], (const float*)d_in[17],
        (float*)d_out);
}

// Round 17
// 44.235 us; speedup vs baseline: 1.0574x; 1.0574x over previous
//
#include <hip/hip_runtime.h>

#define B_N 262144
#define OBS_N 8

typedef __attribute__((ext_vector_type(4))) _Float16 f16x4;
typedef __attribute__((ext_vector_type(2))) __fp16 fp16x2;
typedef __attribute__((ext_vector_type(4))) float f32x4;

#define LOG2E 1.44269504088896340736f

__device__ __forceinline__ float rcpf_(float x){ return __builtin_amdgcn_rcpf(x); }
__device__ __forceinline__ float exp2f_(float x){ return __builtin_amdgcn_exp2f(x); }
// exact for all signs: tanh(x) = 1 - 2/(exp2(2*log2e*x)+1)
__device__ __forceinline__ float tanh_(float x){ return fmaf(-2.0f, rcpf_(exp2f_((2.0f*LOG2E) * x) + 1.0f), 1.0f); }

__device__ __forceinline__ f16x4 pack4(float a, float b, float c, float d){
    fp16x2 lo = __builtin_amdgcn_cvt_pkrtz(a, b);
    fp16x2 hi = __builtin_amdgcn_cvt_pkrtz(c, d);
    f16x4 r;
    r[0] = (_Float16)lo[0]; r[1] = (_Float16)lo[1];
    r[2] = (_Float16)hi[0]; r[3] = (_Float16)hi[1];
    return r;
}

#define MFMA16(a, b, c) __builtin_amdgcn_mfma_f32_16x16x16f16((a), (b), (c), 0, 0, 0)

// Layout (v_mfma_f32_16x16x16_f16):
//   A: lane holds A[row = lane&15][k = 4*(lane>>4)+i]
//   B: lane holds B[k = 4*(lane>>4)+i][col = lane&15]
//   C/D: lane holds C[row = 4*(lane>>4)+r][col = lane&15]
// => D layout == next-GEMM B layout (batch in columns): recurrence needs no shuffle.
//
// FINAL STRUCTURE (R9 = empirical optimum; reproduced at 44.3us in R9/R15):
//   2 col-tiles/wave (2 independent MFMA+cell chains), 4 waves/SIMD,
//   ~104 total unified regs (52 arch + ~48 acc), no spill.
//   All 8 perturbation probes neutral or worse:
//   -VALU (R8) 0, +wave (R10) 0, trans->VALU (R11) -11%, +prefetch regs (R12)
//   -6%, 4-tile (R13) spill -57%, setprio (R14) -3%, anti-phase (R16) -5%.
//   Residual ~19% no-issue = serial MFMA->exp2-chain dependency at the
//   register-feasible ILP x occupancy limit.
__global__ __launch_bounds__(256, 4) void goal_kernel(
    const float* __restrict__ traj,
    const float* __restrict__ obsp,
    const float* __restrict__ h0,
    const float* __restrict__ c0,
    const float* __restrict__ noise,
    const float* __restrict__ encW,
    const float* __restrict__ encb,
    const float* __restrict__ Wih,
    const float* __restrict__ Whh,
    const float* __restrict__ bih,
    const float* __restrict__ bhh,
    const float* __restrict__ jW,
    const float* __restrict__ jb,
    const float* __restrict__ cW,
    const float* __restrict__ hW,
    const float* __restrict__ hb,
    const float* __restrict__ oW,
    const float* __restrict__ ob,
    float* __restrict__ out)
{
    const int lane = threadIdx.x & 63;
    const int wv   = threadIdx.x >> 6;
    const int q    = lane >> 4;
    const int s    = lane & 15;
    const int j4   = q * 4;
    const int base = blockIdx.x * 128 + wv * 32;   // 32 batch cols per wave
    const int colA = base + s;
    const int colB = base + 16 + s;

    // ---- preload (once), f16-compressed ----
    f16x4 ew0h, ew1h, ebh;
    #pragma unroll
    for (int r = 0; r < 4; ++r) {
        ew0h[r] = (_Float16)encW[(j4 + r) * 2 + 0];
        ew1h[r] = (_Float16)encW[(j4 + r) * 2 + 1];
        ebh[r]  = (_Float16)encb[j4 + r];
    }

    // gate exp2-arg pre-scaling folded into weights+bias:
    // i,f,o: * -log2e ; g: * -2log2e
    const float gsc[4] = { -LOG2E, -LOG2E, -2.0f*LOG2E, -LOG2E };

    f16x4 wihA[4], whhA[4], biasH[4];
    #pragma unroll
    for (int m = 0; m < 4; ++m) {
        float4 wa = *(const float4*)(Wih + (16 * m + s) * 16 + j4);
        float4 wb = *(const float4*)(Whh + (16 * m + s) * 16 + j4);
        wihA[m] = pack4(wa.x*gsc[m], wa.y*gsc[m], wa.z*gsc[m], wa.w*gsc[m]);
        whhA[m] = pack4(wb.x*gsc[m], wb.y*gsc[m], wb.z*gsc[m], wb.w*gsc[m]);
        float4 b1 = *(const float4*)(bih + 16 * m + j4);
        float4 b2 = *(const float4*)(bhh + 16 * m + j4);
        biasH[m] = pack4((b1.x+b2.x)*gsc[m], (b1.y+b2.y)*gsc[m],
                         (b1.z+b2.z)*gsc[m], (b1.w+b2.w)*gsc[m]);
    }

    // state (two independent column tiles)
    f32x4 cA = *(const f32x4*)(c0 + colA * 16 + j4);
    f32x4 cB = *(const f32x4*)(c0 + colB * 16 + j4);
    float4 hA0 = *(const float4*)(h0 + colA * 16 + j4);
    float4 hB0 = *(const float4*)(h0 + colB * 16 + j4);
    f16x4 hA = pack4(hA0.x, hA0.y, hA0.z, hA0.w);
    f16x4 hB = pack4(hB0.x, hB0.y, hB0.z, hB0.w);

    float2 nzA = *(const float2*)(noise + colA * 2);
    float2 nzB = *(const float2*)(noise + colB * 2);

    const float NEG2L2E = -2.0f * LOG2E;

    // ---------------- LSTM encoder ----------------
    float2 xA = *(const float2*)(traj + colA * 2);
    float2 xB = *(const float2*)(traj + colB * 2);

    #pragma unroll 1
    for (int t = 0; t < OBS_N; ++t) {
        float2 nxA, nxB;
        if (t < OBS_N - 1) {
            nxA = *(const float2*)(traj + (t + 1) * (B_N * 2) + colA * 2);
            nxB = *(const float2*)(traj + (t + 1) * (B_N * 2) + colB * 2);
        }

        // e = relu(encW x + encb) in packed f16 — direct B-fragment
        _Float16 ax = (_Float16)xA.x, ay = (_Float16)xA.y;
        _Float16 bx = (_Float16)xB.x, by = (_Float16)xB.y;
        f16x4 xxA = { ax, ax, ax, ax }, yyA = { ay, ay, ay, ay };
        f16x4 xxB = { bx, bx, bx, bx }, yyB = { by, by, by, by };
        f16x4 eA = ew0h * xxA + ew1h * yyA + ebh;
        f16x4 eB = ew0h * xxB + ew1h * yyB + ebh;
        #pragma unroll
        for (int r = 0; r < 4; ++r) {
            eA[r] = eA[r] > (_Float16)0 ? eA[r] : (_Float16)0;
            eB[r] = eB[r] > (_Float16)0 ? eB[r] : (_Float16)0;
        }

        f32x4 gA[4], gB[4];
        #pragma unroll
        for (int m = 0; m < 4; ++m) {
            f32x4 bv;
            bv[0] = (float)biasH[m][0]; bv[1] = (float)biasH[m][1];
            bv[2] = (float)biasH[m][2]; bv[3] = (float)biasH[m][3];
            gA[m] = MFMA16(wihA[m], eA, bv);
            gA[m] = MFMA16(whhA[m], hA, gA[m]);
            gB[m] = MFMA16(wihA[m], eB, bv);
            gB[m] = MFMA16(whhA[m], hB, gB[m]);
        }

        // cell: gates are pre-scaled exp2 args; two independent chains
        float hnA[4], hnB[4];
        #pragma unroll
        for (int r = 0; r < 4; ++r) {
            {
                float Ei = exp2f_(gA[0][r]);
                float Ef = exp2f_(gA[1][r]);
                float Eg = exp2f_(gA[2][r]);
                float Eo = exp2f_(gA[3][r]);
                float pi = 1.0f + Ei, pg = 1.0f + Eg, pf = 1.0f + Ef;
                float m_ = pi * pg;
                float R1 = rcpf_(m_ * pf);
                float cn = fmaf(cA[r], m_, fmaf(-Eg, pf, pf)) * R1;
                cA[r] = cn;
                float Ec = exp2f_(NEG2L2E * cn);
                float R2 = rcpf_((1.0f + Ec) * (1.0f + Eo));
                hnA[r] = fmaf(-Ec, R2, R2);
            }
            {
                float Ei = exp2f_(gB[0][r]);
                float Ef = exp2f_(gB[1][r]);
                float Eg = exp2f_(gB[2][r]);
                float Eo = exp2f_(gB[3][r]);
                float pi = 1.0f + Ei, pg = 1.0f + Eg, pf = 1.0f + Ef;
                float m_ = pi * pg;
                float R1 = rcpf_(m_ * pf);
                float cn = fmaf(cB[r], m_, fmaf(-Eg, pf, pf)) * R1;
                cB[r] = cn;
                float Ec = exp2f_(NEG2L2E * cn);
                float R2 = rcpf_((1.0f + Ec) * (1.0f + Eo));
                hnB[r] = fmaf(-Ec, R2, R2);
            }
        }
        hA = pack4(hnA[0], hnA[1], hnA[2], hnA[3]);
        hB = pack4(hnB[0], hnB[1], hnB[2], hnB[3]);

        if (t < OBS_N - 1) { xA = nxA; xB = nxB; }
    }

    // ---------------- MAF sample ----------------
    float x0A = nzA.x, x1A = nzA.y;
    float x0B = nzB.x, x1B = nzB.y;

    #pragma unroll 1
    for (int kf = 3; kf >= 0; --kf) {
        float tA = x0A; x0A = x1A; x1A = tA;
        float tB = x0B; x0B = x1B; x1B = tB;

        float ob0 = ob[kf*4 + 0], ob1 = ob[kf*4 + 1];
        float ob2 = ob[kf*4 + 2], ob3 = ob[kf*4 + 3] * 0.2f;
        // i=0: rows 0,2 fully masked -> flow constants
        float ea0 = exp2f_(7.2134752044f * tanh_(ob2 * 0.2f));  // e^{5 tanh(ob2/5)}
        x0A = fmaf(x0A, ea0, ob0);
        x0B = fmaf(x0B, ea0, ob0);

        // per-flow weights (shared by both column tiles)
        float4 cw = *(const float4*)(cW + kf * 256 + s * 16 + j4);
        f16x4 cwA = pack4(cw.x, cw.y, cw.z, cw.w);
        float4 hw = *(const float4*)(hW + kf * 256 + s * 16 + j4);
        f16x4 hwA = pack4(hw.x, hw.y, hw.z, hw.w);
        // oW rows replicated period-4; row 3 pre-scaled by 1/CLAMP
        float osc = ((s & 3) == 3) ? 0.2f : 1.0f;
        float4 ow = *(const float4*)(oW + kf * 64 + (s & 3) * 16 + j4);
        f16x4 owA = pack4(ow.x * osc, ow.y * osc, ow.z * osc, ow.w * osc);

        // i=1: h1 = relu(jW0*x0 + jb + cW@h)
        f32x4 a1A, a1B;
        #pragma unroll
        for (int r = 0; r < 4; ++r) {
            float jwv = jW[kf * 32 + (j4 + r) * 2];
            float jbv = jb[kf * 16 + j4 + r];
            a1A[r] = fmaf(jwv, x0A, jbv);
            a1B[r] = fmaf(jwv, x0B, jbv);
        }
        a1A = MFMA16(cwA, hA, a1A);
        a1B = MFMA16(cwA, hB, a1B);
        f16x4 h1A = pack4(fmaxf(a1A[0],0.f), fmaxf(a1A[1],0.f), fmaxf(a1A[2],0.f), fmaxf(a1A[3],0.f));
        f16x4 h1B = pack4(fmaxf(a1B[0],0.f), fmaxf(a1B[1],0.f), fmaxf(a1B[2],0.f), fmaxf(a1B[3],0.f));

        f32x4 a2A, a2B;
        #pragma unroll
        for (int r = 0; r < 4; ++r) { float hbv = hb[kf * 16 + j4 + r]; a2A[r] = hbv; a2B[r] = hbv; }
        a2A = MFMA16(hwA, h1A, a2A);
        a2B = MFMA16(hwA, h1B, a2B);
        f16x4 h2A = pack4(fmaxf(a2A[0],0.f), fmaxf(a2A[1],0.f), fmaxf(a2A[2],0.f), fmaxf(a2A[3],0.f));
        f16x4 h2B = pack4(fmaxf(a2B[0],0.f), fmaxf(a2B[1],0.f), fmaxf(a2B[2],0.f), fmaxf(a2B[3],0.f));

        f32x4 a3A, a3B;
        a3A[0] = ob0; a3A[1] = ob1; a3A[2] = ob2; a3A[3] = ob3;
        a3B = a3A;
        a3A = MFMA16(owA, h2A, a3A);
        a3B = MFMA16(owA, h2B, a3B);

        // row 3 already × 0.2 ; x1 = x1*e^{5 tanh(.)} + m1
        x1A = fmaf(x1A, exp2f_(7.2134752044f * tanh_(a3A[3])), a3A[1]);
        x1B = fmaf(x1B, exp2f_(7.2134752044f * tanh_(a3B[3])), a3B[1]);
    }

    if (q == 0) {
        float2 ppA = *(const float2*)(obsp + (OBS_N - 1) * (B_N * 2) + colA * 2);
        float2 ppB = *(const float2*)(obsp + (OBS_N - 1) * (B_N * 2) + colB * 2);
        float2 oA; oA.x = x0A + ppA.x; oA.y = x1A + ppA.y;
        float2 oB; oB.x = x0B + ppB.x; oB.y = x1B + ppB.y;
        *(float2*)(out + colA * 2) = oA;
        *(float2*)(out + colB * 2) = oB;
    }
}

extern "C" void kernel_launch(void* const* d_in, const int* in_sizes, int n_in,
                              void* d_out, int out_size, void* d_ws, size_t ws_size,
                              hipStream_t stream) {
    goal_kernel<<<B_N / 128, 256, 0, stream>>>(
        (const float*)d_in[0],  (const float*)d_in[1],  (const float*)d_in[2],
        (const float*)d_in[3],  (const float*)d_in[4],  (const float*)d_in[5],
        (const float*)d_in[6],  (const float*)d_in[7],  (const float*)d_in[8],
        (const float*)d_in[9],  (const float*)d_in[10], (const float*)d_in[11],
        (const float*)d_in[12], (const float*)d_in[13], (const float*)d_in[14],
        (const float*)d_in[15], (const float*)d_in[16], (const float*)d_in[17],
        (float*)d_out);
}